// Round 11
// baseline (663.337 us; speedup 1.0000x reference)
//
#include <hip/hip_runtime.h>
#include <cstdint>
#include <cstddef>

typedef unsigned short u16;
typedef __attribute__((ext_vector_type(8))) short short8;
typedef __attribute__((ext_vector_type(8))) u16 ushort8;
typedef __attribute__((ext_vector_type(4))) float float4_t;

#define BB 8
#define NN 8192
#define DD 64
#define NTILES 64            // 8192 / 128 column tiles
#define TILE_SHORTS 8192     // 128 points * 64 k (bf16)
#define LDS_STRIDE 68        // 64 floats + 4 pad (bank spread)

__device__ inline u16 f32_to_bf16(float f) {
  unsigned u = __float_as_uint(f);
  u += 0x7FFFu + ((u >> 16) & 1u);   // RNE
  return (u16)(u >> 16);
}

__device__ inline unsigned enc_ord(float f) {
  unsigned u = __float_as_uint(f);
  return (u & 0x80000000u) ? ~u : (u | 0x80000000u);
}
__device__ inline float dec_ord(unsigned u) {
  return __uint_as_float((u & 0x80000000u) ? (u & 0x7fffffffu) : ~u);
}

// ---------------------------------------------------------------------------
// K1: one block = one 128x64 tile. Coalesced read-once -> LDS -> swizzled
// bf16 tile (MFMA fragment chunk order) + 0.5*|row|^2. Zeroes out[] and, in
// the fallback path, the ordered-uint max buffers.  [verified R6-R10]
// ---------------------------------------------------------------------------
__global__ __launch_bounds__(256) void pre_kernel(
    const float* __restrict__ x, const float* __restrict__ y,
    u16* __restrict__ xs, u16* __restrict__ ys,
    float* __restrict__ x2h, float* __restrict__ y2h,
    unsigned* __restrict__ rowmax_u, unsigned* __restrict__ colmax_u,
    float* __restrict__ out, const int use_part)
{
  __shared__ float stage[128 * LDS_STRIDE];   // 34 KB

  const int bid = blockIdx.x;          // 1024: 0..511 -> x, 512..1023 -> y
  const int tid = threadIdx.x;

  if (!use_part) {
    if (bid < 256)      colmax_u[(bid << 8) | tid] = 0u;
    else if (bid < 512) rowmax_u[((bid - 256) << 8) | tid] = 0u;
  }
  if (bid == 0 && tid == 0) out[0] = 0.f;

  const bool isY = bid >= 512;
  const int t = bid & 511;             // tile id = b*64 + nt
  const float* src = (isY ? y : x) + (size_t)t * (128 * DD);
  u16* dst = (isY ? ys : xs) + (size_t)t * TILE_SHORTS;
  float* s2 = (isY ? y2h : x2h) + t * 128;

#pragma unroll
  for (int c = 0; c < 8; ++c) {
    const int idx = c * 256 + tid;     // float4 index within tile (0..2047)
    float4 f = ((const float4*)src)[idx];
    const int r = idx >> 4, kc = idx & 15;
    *(float4*)&stage[r * LDS_STRIDE + kc * 4] = f;
  }
  __syncthreads();

  {
    const int r = tid >> 1, half = tid & 1;
    const float* rp = &stage[r * LDS_STRIDE + half * 32];
    float ss = 0.f;
#pragma unroll
    for (int k = 0; k < 8; ++k) {
      float4 f = *(const float4*)&rp[k * 4];
      ss += f.x*f.x + f.y*f.y + f.z*f.z + f.w*f.w;
    }
    ss += __shfl_xor(ss, 1);
    if (half == 0) s2[r] = 0.5f * ss;
  }

  {
    const int w = tid >> 6, lane = tid & 63;
    const int qq = lane >> 4, rl = lane & 15;
#pragma unroll
    for (int u = 0; u < 4; ++u) {
      const int chunk = w * 4 + u;
      const int I = chunk >> 1, s = chunk & 1;
      const float* rp = &stage[(I*16 + rl) * LDS_STRIDE + s*32 + qq*8];
      ushort8 o;
#pragma unroll
      for (int j = 0; j < 8; ++j) o[j] = f32_to_bf16(rp[j]);
      *(ushort8*)(dst + chunk*512 + lane*8) = o;
    }
  }
}

// ---------------------------------------------------------------------------
// K2: main — R3 loop + y2-in-C-init (pure-max epilogue), at 3 blocks/CU.
// Register model (R4/R9/R10 evidence): VGPR_Count excludes the 32 AGPRs the
// acc bank occupies in the unified file; true live total ~164. launch_bounds
// (256,3) caps the budget at 170 >= 164 -> fits, runtime schedules exactly
// 3 blocks/CU (every round's occupancy tracked the declared 2nd arg).
// Grid 1536 = 8 b (XCD-affine) x 64 nt x 3 h (22/21/21 col-tiles) = exactly
// 2 full rounds of 768 resident blocks — uniform residency, no ragged tail.
// DO NOT add acc double-buffering / unrolling (R4/R6/R8 all lost).
// ---------------------------------------------------------------------------
__global__ __launch_bounds__(256, 3) void main_kernel(
    const u16* __restrict__ xs, const u16* __restrict__ ys,
    const float* __restrict__ x2h, const float* __restrict__ y2h,
    float* __restrict__ rowpart, float* __restrict__ colpart,
    unsigned* __restrict__ rowmax_u, unsigned* __restrict__ colmax_u,
    const int use_part)
{
  __shared__ float rowbuf[4][128];

  const int bid = blockIdx.x;            // 1536
  const int b   = bid & 7;               // XCD-affine
  const int nt  = (bid >> 3) & 63;
  const int h   = bid >> 9;              // 0..2 column third
  const int mt_start = (h == 0) ? 0 : (h == 1 ? 22 : 43);
  const int mt_end   = (h == 0) ? 22 : (h == 1 ? 43 : 64);
  const int tid = threadIdx.x;
  const int w = tid >> 6, lane = tid & 63;   // w = column-slice owner
  const int l15 = lane & 15, q = lane >> 4;
  const int n0 = nt << 7;

  // ---- A fragments: all 128 rows, both K-halves, pinned in registers ----
  const u16* xs_tile = xs + (size_t)((b << 6) | nt) * TILE_SHORTS;
  short8 afr[8][2];
#pragma unroll
  for (int i = 0; i < 8; ++i)
#pragma unroll
    for (int s = 0; s < 2; ++s)
      afr[i][s] = *(const short8*)(xs_tile + (i*2 + s)*512 + lane*8);

  // ---- -x2/2 per row (fp32 exact, combined with -y2/2 in C-init) ----
  float4_t negx2[8];
  const float* x2b = x2h + b*NN + n0;
#pragma unroll
  for (int i = 0; i < 8; ++i) {
    float4_t v = *(const float4_t*)(x2b + i*16 + q*4);
    negx2[i] = {-v[0], -v[1], -v[2], -v[3]};
  }

  float rowmax[8][4];
#pragma unroll
  for (int i = 0; i < 8; ++i)
#pragma unroll
    for (int r = 0; r < 4; ++r) rowmax[i][r] = -3.0e38f;

  const float* y2b = y2h + b*NN;
  const u16* ys_b  = ys + (size_t)(b << 6) * TILE_SHORTS;
  float* colp      = colpart + (size_t)((b << 6) | nt) * NN;
  unsigned* colu   = colmax_u + b*NN;

  // ---- register prefetch for mt_start ----
  short8 bcur[2][2];
  float y2cur[2];
#pragma unroll
  for (int j = 0; j < 2; ++j) {
#pragma unroll
    for (int s = 0; s < 2; ++s)
      bcur[j][s] = *(const short8*)(ys_b + (size_t)mt_start*TILE_SHORTS
                                    + ((2*w + j)*2 + s)*512 + lane*8);
    y2cur[j] = y2b[mt_start*128 + w*32 + j*16 + l15];
  }

  for (int mt = mt_start; mt < mt_end; ++mt) {
    // prefetch mt+1 (clamped; uniform predicate-free codegen)
    const int mtn = (mt + 1 < mt_end) ? (mt + 1) : mt_start;
    short8 bnext[2][2];
    float y2next[2];
    const u16* g = ys_b + (size_t)mtn * TILE_SHORTS;
#pragma unroll
    for (int j = 0; j < 2; ++j) {
#pragma unroll
      for (int s = 0; s < 2; ++s)
        bnext[j][s] = *(const short8*)(g + ((2*w + j)*2 + s)*512 + lane*8);
      y2next[j] = y2b[mtn*128 + w*32 + j*16 + l15];
    }

    float cmax[2];
#pragma unroll
    for (int j = 0; j < 2; ++j) {
      // acc = xy - x2/2 - y2/2 = -d^2/2 (C-init subs are independent of
      // prior MFMAs -> overlap the matrix pipe instead of trailing it)
      const float y2j = y2cur[j];
      float4_t acc[8];
#pragma unroll
      for (int i = 0; i < 8; ++i) {
        float4_t ci = {negx2[i][0] - y2j, negx2[i][1] - y2j,
                       negx2[i][2] - y2j, negx2[i][3] - y2j};
        acc[i] = __builtin_amdgcn_mfma_f32_16x16x32_bf16(afr[i][0], bcur[j][0], ci, 0, 0, 0);
      }
#pragma unroll
      for (int i = 0; i < 8; ++i)
        acc[i] = __builtin_amdgcn_mfma_f32_16x16x32_bf16(afr[i][1], bcur[j][1], acc[i], 0, 0, 0);

      // col side: pure max over rows in-lane
      float m01 = fmaxf(fmaxf(acc[0][0], acc[0][1]), fmaxf(acc[0][2], acc[0][3]));
#pragma unroll
      for (int i = 1; i < 8; ++i) {
        float mi = fmaxf(fmaxf(acc[i][0], acc[i][1]), fmaxf(acc[i][2], acc[i][3]));
        m01 = fmaxf(m01, mi);
      }
      cmax[j] = m01;

      // row side: pure max (acc already = -d^2/2)
#pragma unroll
      for (int i = 0; i < 8; ++i)
#pragma unroll
        for (int r = 0; r < 4; ++r)
          rowmax[i][r] = fmaxf(rowmax[i][r], acc[i][r]);
    }

    // col-max: combine q-groups (rows) via shuffles; wave-private, no barrier
#pragma unroll
    for (int j = 0; j < 2; ++j) {
      cmax[j] = fmaxf(cmax[j], __shfl_xor(cmax[j], 16));
      cmax[j] = fmaxf(cmax[j], __shfl_xor(cmax[j], 32));
    }
    float cv = (q & 1) ? cmax[1] : cmax[0];
    const int m = (mt << 7) + w*32 + q*16 + l15;   // valid for q<2
    if (q < 2) {
      if (use_part) colp[m] = cv;
      else          atomicMax(&colu[m], enc_ord(cv));
    }

#pragma unroll
    for (int j = 0; j < 2; ++j) {
#pragma unroll
      for (int s = 0; s < 2; ++s) bcur[j][s] = bnext[j][s];
      y2cur[j] = y2next[j];
    }
  }

  // ---- row side finalize: shfl over cols (l15), then 4-wave LDS combine ----
#pragma unroll
  for (int i = 0; i < 8; ++i)
#pragma unroll
    for (int r = 0; r < 4; ++r) {
      float v = rowmax[i][r];
      v = fmaxf(v, __shfl_xor(v, 1));
      v = fmaxf(v, __shfl_xor(v, 2));
      v = fmaxf(v, __shfl_xor(v, 4));
      v = fmaxf(v, __shfl_xor(v, 8));
      rowmax[i][r] = v;
    }
  if (l15 == 0) {
#pragma unroll
    for (int i = 0; i < 8; ++i)
#pragma unroll
      for (int r = 0; r < 4; ++r)
        rowbuf[w][i*16 + q*4 + r] = rowmax[i][r];
  }
  __syncthreads();
  if (tid < 128) {
    float v = fmaxf(fmaxf(rowbuf[0][tid], rowbuf[1][tid]),
                    fmaxf(rowbuf[2][tid], rowbuf[3][tid]));   // -min(d^2)/2
    if (use_part) rowpart[(size_t)(h*512 + (b << 6) + nt) * 128 + tid] = v;
    else          atomicMax(&rowmax_u[b*NN + n0 + tid], enc_ord(v));
  }
}

// ---------------------------------------------------------------------------
// K3: col combine over 64 nt + sqrt; row combine over 3 h + sqrt; block sum;
// atomicAdd scaled result into out. (both sides carry -d^2/2)
// ---------------------------------------------------------------------------
__global__ __launch_bounds__(256) void reduce_kernel(
    const float* __restrict__ rowpart, const float* __restrict__ colpart,
    const unsigned* __restrict__ rowmax_u, const unsigned* __restrict__ colmax_u,
    float* __restrict__ out, const int use_part)
{
  const int bid = blockIdx.x;          // 256
  const int tid = threadIdx.x;
  const int g = bid*256 + tid;         // 0..65535
  const int b = g >> 13, m = g & (NN - 1);

  float vc, vr;
  if (use_part) {
    vc = -3.0e38f;
#pragma unroll 8
    for (int nt = 0; nt < 64; ++nt)
      vc = fmaxf(vc, colpart[(size_t)((b << 6) | nt) * NN + m]);
    const int nt = m >> 7, r = m & 127;
    float r0 = rowpart[(size_t)(0*512 + (b << 6) + nt) * 128 + r];
    float r1 = rowpart[(size_t)(1*512 + (b << 6) + nt) * 128 + r];
    float r2 = rowpart[(size_t)(2*512 + (b << 6) + nt) * 128 + r];
    vr = fmaxf(fmaxf(r0, r1), r2);
  } else {
    vc = dec_ord(colmax_u[g]);
    vr = dec_ord(rowmax_u[g]);
  }
  float s = sqrtf(fmaxf(-2.f * vc, 0.f))   // nearest-x for this y
          + sqrtf(fmaxf(-2.f * vr, 0.f));  // nearest-y for this x

#pragma unroll
  for (int d = 1; d < 64; d <<= 1) s += __shfl_xor(s, d);
  __shared__ float wsum[4];
  if ((tid & 63) == 0) wsum[tid >> 6] = s;
  __syncthreads();
  if (tid == 0)
    atomicAdd(out, (wsum[0] + wsum[1] + wsum[2] + wsum[3]) * (1.0f / 65536.0f));
}

// ---------------------------------------------------------------------------
extern "C" void kernel_launch(void* const* d_in, const int* in_sizes, int n_in,
                              void* d_out, int out_size, void* d_ws, size_t ws_size,
                              hipStream_t stream) {
  const float* x = (const float*)d_in[0];
  const float* y = (const float*)d_in[1];
  float* out = (float*)d_out;

  char* p = (char*)d_ws;
  u16* xs = (u16*)p;            p += (size_t)512 * 16384;   // 8 MiB
  u16* ys = (u16*)p;            p += (size_t)512 * 16384;   // 8 MiB
  float* x2h = (float*)p;       p += (size_t)65536 * 4;
  float* y2h = (float*)p;       p += (size_t)65536 * 4;
  char* tail = p;
  // partial path: colpart 16 MiB + rowpart 768 KiB
  float* colpart = (float*)tail;
  float* rowpart = (float*)(tail + (size_t)512 * 8192 * 4);
  // atomic fallback: two 256 KiB ordered-uint max buffers
  unsigned* colmax_u = (unsigned*)tail;
  unsigned* rowmax_u = (unsigned*)(tail + (size_t)65536 * 4);
  const size_t need_part = (size_t)(tail - (char*)d_ws) +
                           (size_t)512 * 8192 * 4 + (size_t)1536 * 128 * 4;
  const int use_part = (ws_size >= need_part) ? 1 : 0;

  pre_kernel<<<dim3(1024), dim3(256), 0, stream>>>(x, y, xs, ys, x2h, y2h,
                                                   rowmax_u, colmax_u, out,
                                                   use_part);
  main_kernel<<<dim3(1536), dim3(256), 0, stream>>>(xs, ys, x2h, y2h,
                                                    rowpart, colpart,
                                                    rowmax_u, colmax_u,
                                                    use_part);
  reduce_kernel<<<dim3(256), dim3(256), 0, stream>>>(rowpart, colpart,
                                                     rowmax_u, colmax_u,
                                                     out, use_part);
}

// Round 12
// 242.221 us; speedup vs baseline: 2.7386x; 2.7386x over previous
//
#include <hip/hip_runtime.h>
#include <cstdint>
#include <cstddef>

typedef unsigned short u16;
typedef __attribute__((ext_vector_type(8))) short short8;
typedef __attribute__((ext_vector_type(8))) u16 ushort8;
typedef __attribute__((ext_vector_type(4))) float float4_t;

#define BB 8
#define NN 8192
#define DD 64
#define NTILES 64            // 8192 / 128 column tiles
#define TILE_SHORTS 8192     // 128 points * 64 k (bf16)
#define LDS_STRIDE 68        // 64 floats + 4 pad (bank spread)

__device__ inline u16 f32_to_bf16(float f) {
  unsigned u = __float_as_uint(f);
  u += 0x7FFFu + ((u >> 16) & 1u);   // RNE
  return (u16)(u >> 16);
}

__device__ inline unsigned enc_ord(float f) {
  unsigned u = __float_as_uint(f);
  return (u & 0x80000000u) ? ~u : (u | 0x80000000u);
}
__device__ inline float dec_ord(unsigned u) {
  return __uint_as_float((u & 0x80000000u) ? (u & 0x7fffffffu) : ~u);
}

// ---------------------------------------------------------------------------
// K1: one block = one 128x64 tile. Coalesced read-once -> LDS -> swizzled
// bf16 tile (MFMA fragment chunk order) + 0.5*|row|^2. Zeroes out[] and, in
// the fallback path, the ordered-uint max buffers.  [verified R6-R11]
// ---------------------------------------------------------------------------
__global__ __launch_bounds__(256) void pre_kernel(
    const float* __restrict__ x, const float* __restrict__ y,
    u16* __restrict__ xs, u16* __restrict__ ys,
    float* __restrict__ x2h, float* __restrict__ y2h,
    unsigned* __restrict__ rowmax_u, unsigned* __restrict__ colmax_u,
    float* __restrict__ out, const int use_part)
{
  __shared__ float stage[128 * LDS_STRIDE];   // 34 KB

  const int bid = blockIdx.x;          // 1024: 0..511 -> x, 512..1023 -> y
  const int tid = threadIdx.x;

  if (!use_part) {
    if (bid < 256)      colmax_u[(bid << 8) | tid] = 0u;
    else if (bid < 512) rowmax_u[((bid - 256) << 8) | tid] = 0u;
  }
  if (bid == 0 && tid == 0) out[0] = 0.f;

  const bool isY = bid >= 512;
  const int t = bid & 511;             // tile id = b*64 + nt
  const float* src = (isY ? y : x) + (size_t)t * (128 * DD);
  u16* dst = (isY ? ys : xs) + (size_t)t * TILE_SHORTS;
  float* s2 = (isY ? y2h : x2h) + t * 128;

#pragma unroll
  for (int c = 0; c < 8; ++c) {
    const int idx = c * 256 + tid;     // float4 index within tile (0..2047)
    float4 f = ((const float4*)src)[idx];
    const int r = idx >> 4, kc = idx & 15;
    *(float4*)&stage[r * LDS_STRIDE + kc * 4] = f;
  }
  __syncthreads();

  {
    const int r = tid >> 1, half = tid & 1;
    const float* rp = &stage[r * LDS_STRIDE + half * 32];
    float ss = 0.f;
#pragma unroll
    for (int k = 0; k < 8; ++k) {
      float4 f = *(const float4*)&rp[k * 4];
      ss += f.x*f.x + f.y*f.y + f.z*f.z + f.w*f.w;
    }
    ss += __shfl_xor(ss, 1);
    if (half == 0) s2[r] = 0.5f * ss;
  }

  {
    const int w = tid >> 6, lane = tid & 63;
    const int qq = lane >> 4, rl = lane & 15;
#pragma unroll
    for (int u = 0; u < 4; ++u) {
      const int chunk = w * 4 + u;
      const int I = chunk >> 1, s = chunk & 1;
      const float* rp = &stage[(I*16 + rl) * LDS_STRIDE + s*32 + qq*8];
      ushort8 o;
#pragma unroll
      for (int j = 0; j < 8; ++j) o[j] = f32_to_bf16(rp[j]);
      *(ushort8*)(dst + chunk*512 + lane*8) = o;
    }
  }
}

// ---------------------------------------------------------------------------
// K2: main — R9/R11 loop (C-init carries exact fp32 -(x^2+y^2)/2 -> acc =
// -d^2/2, pure-max epilogue) at (256,2), grid 1024 = 8 b x 64 nt x 2 h,
// with a MANUAL 2x-unrolled PING-PONG K-loop: body A prefetches set1 and
// computes from set0; body B prefetches set0 and computes from set1.
// No bcur=bnext copies -> first use of a set no longer sits behind a
// vmcnt(0) drain of the other set's in-flight prefetch (AITER-style
// fine-grained waits). ZERO register delta: b0+b1 = the same 32 regs the
// old bcur+bnext pair occupied.
// Register model (R4/R10/R11): true live total ~190-200 unified regs
// (VGPR_Count excludes AGPR-banked values) -> 2 waves/SIMD is the ceiling;
// do NOT request 3+ waves (spills, 10x cost) or add acc banks.
// ---------------------------------------------------------------------------
__global__ __launch_bounds__(256, 2) void main_kernel(
    const u16* __restrict__ xs, const u16* __restrict__ ys,
    const float* __restrict__ x2h, const float* __restrict__ y2h,
    float* __restrict__ rowpart, float* __restrict__ colpart,
    unsigned* __restrict__ rowmax_u, unsigned* __restrict__ colmax_u,
    const int use_part)
{
  __shared__ float rowbuf[4][128];

  const int bid = blockIdx.x;            // 1024
  const int b   = bid & 7;               // XCD-affine
  const int nt  = (bid >> 3) & 63;
  const int h   = bid >> 9;              // 0..1 column half
  const int mt_start = h << 5, mt_end = mt_start + 32;   // 32 iters (even)
  const int tid = threadIdx.x;
  const int w = tid >> 6, lane = tid & 63;   // w = column-slice owner
  const int l15 = lane & 15, q = lane >> 4;
  const int n0 = nt << 7;

  // ---- A fragments: all 128 rows, both K-halves, pinned in registers ----
  const u16* xs_tile = xs + (size_t)((b << 6) | nt) * TILE_SHORTS;
  short8 afr[8][2];
#pragma unroll
  for (int i = 0; i < 8; ++i)
#pragma unroll
    for (int s = 0; s < 2; ++s)
      afr[i][s] = *(const short8*)(xs_tile + (i*2 + s)*512 + lane*8);

  // ---- -x2/2 per row (fp32 exact, combined with -y2/2 in C-init) ----
  float4_t negx2[8];
  const float* x2b = x2h + b*NN + n0;
#pragma unroll
  for (int i = 0; i < 8; ++i) {
    float4_t v = *(const float4_t*)(x2b + i*16 + q*4);
    negx2[i] = {-v[0], -v[1], -v[2], -v[3]};
  }

  float rowmax[8][4];
#pragma unroll
  for (int i = 0; i < 8; ++i)
#pragma unroll
    for (int r = 0; r < 4; ++r) rowmax[i][r] = -3.0e38f;

  const float* y2b = y2h + b*NN;
  const u16* ys_b  = ys + (size_t)(b << 6) * TILE_SHORTS;
  float* colp      = colpart + (size_t)((b << 6) | nt) * NN;
  unsigned* colu   = colmax_u + b*NN;

  // ---- ping-pong B-sets (32 regs total, same as old bcur+bnext) ----
  short8 b0[2][2], b1[2][2];
  float y20[2], y21[2];

#define PREFETCH(SET, Y2S, MT)                                                 \
  do {                                                                         \
    const u16* g_ = ys_b + (size_t)(MT) * TILE_SHORTS;                         \
    _Pragma("unroll") for (int j = 0; j < 2; ++j) {                            \
      _Pragma("unroll") for (int s = 0; s < 2; ++s)                            \
        SET[j][s] = *(const short8*)(g_ + ((2*w + j)*2 + s)*512 + lane*8);     \
      Y2S[j] = y2b[(MT)*128 + w*32 + j*16 + l15];                              \
    }                                                                          \
  } while (0)

#define COMPUTE(SET, Y2S, MT)                                                  \
  do {                                                                         \
    float cmax[2];                                                             \
    _Pragma("unroll") for (int j = 0; j < 2; ++j) {                            \
      const float y2j = Y2S[j];                                                \
      float4_t acc[8];                                                         \
      _Pragma("unroll") for (int i = 0; i < 8; ++i) {                          \
        float4_t ci = {negx2[i][0] - y2j, negx2[i][1] - y2j,                   \
                       negx2[i][2] - y2j, negx2[i][3] - y2j};                  \
        acc[i] = __builtin_amdgcn_mfma_f32_16x16x32_bf16(afr[i][0], SET[j][0], ci, 0, 0, 0); \
      }                                                                        \
      _Pragma("unroll") for (int i = 0; i < 8; ++i)                            \
        acc[i] = __builtin_amdgcn_mfma_f32_16x16x32_bf16(afr[i][1], SET[j][1], acc[i], 0, 0, 0); \
      float m01 = fmaxf(fmaxf(acc[0][0], acc[0][1]), fmaxf(acc[0][2], acc[0][3])); \
      _Pragma("unroll") for (int i = 1; i < 8; ++i) {                          \
        float mi = fmaxf(fmaxf(acc[i][0], acc[i][1]), fmaxf(acc[i][2], acc[i][3])); \
        m01 = fmaxf(m01, mi);                                                  \
      }                                                                        \
      cmax[j] = m01;                                                           \
      _Pragma("unroll") for (int i = 0; i < 8; ++i)                            \
        _Pragma("unroll") for (int r = 0; r < 4; ++r)                          \
          rowmax[i][r] = fmaxf(rowmax[i][r], acc[i][r]);                       \
    }                                                                          \
    _Pragma("unroll") for (int j = 0; j < 2; ++j) {                            \
      cmax[j] = fmaxf(cmax[j], __shfl_xor(cmax[j], 16));                       \
      cmax[j] = fmaxf(cmax[j], __shfl_xor(cmax[j], 32));                       \
    }                                                                          \
    float cv = (q & 1) ? cmax[1] : cmax[0];                                    \
    const int m_ = ((MT) << 7) + w*32 + q*16 + l15;                            \
    if (q < 2) {                                                               \
      if (use_part) colp[m_] = cv;                                             \
      else          atomicMax(&colu[m_], enc_ord(cv));                         \
    }                                                                          \
  } while (0)

  // prologue: stage set0 with tile mt_start
  PREFETCH(b0, y20, mt_start);

  for (int mt = mt_start; mt < mt_end; mt += 2) {
    const int mtp1 = mt + 1;                                   // < mt_end
    const int mtp2 = (mt + 2 < mt_end) ? (mt + 2) : mt_start;  // clamp
    PREFETCH(b1, y21, mtp1);     // in flight across COMPUTE(b0)
    COMPUTE(b0, y20, mt);
    PREFETCH(b0, y20, mtp2);     // in flight across COMPUTE(b1)
    COMPUTE(b1, y21, mtp1);
  }

#undef PREFETCH
#undef COMPUTE

  // ---- row side finalize: shfl over cols (l15), then 4-wave LDS combine ----
#pragma unroll
  for (int i = 0; i < 8; ++i)
#pragma unroll
    for (int r = 0; r < 4; ++r) {
      float v = rowmax[i][r];
      v = fmaxf(v, __shfl_xor(v, 1));
      v = fmaxf(v, __shfl_xor(v, 2));
      v = fmaxf(v, __shfl_xor(v, 4));
      v = fmaxf(v, __shfl_xor(v, 8));
      rowmax[i][r] = v;
    }
  if (l15 == 0) {
#pragma unroll
    for (int i = 0; i < 8; ++i)
#pragma unroll
      for (int r = 0; r < 4; ++r)
        rowbuf[w][i*16 + q*4 + r] = rowmax[i][r];
  }
  __syncthreads();
  if (tid < 128) {
    float v = fmaxf(fmaxf(rowbuf[0][tid], rowbuf[1][tid]),
                    fmaxf(rowbuf[2][tid], rowbuf[3][tid]));   // -min(d^2)/2
    if (use_part) rowpart[(size_t)((h << 9) | (b << 6) | nt) * 128 + tid] = v;
    else          atomicMax(&rowmax_u[b*NN + n0 + tid], enc_ord(v));
  }
}

// ---------------------------------------------------------------------------
// K3: col combine over 64 nt + sqrt; row combine over 2 h + sqrt; block sum;
// atomicAdd scaled result into out. (both sides carry -d^2/2)
// ---------------------------------------------------------------------------
__global__ __launch_bounds__(256) void reduce_kernel(
    const float* __restrict__ rowpart, const float* __restrict__ colpart,
    const unsigned* __restrict__ rowmax_u, const unsigned* __restrict__ colmax_u,
    float* __restrict__ out, const int use_part)
{
  const int bid = blockIdx.x;          // 256
  const int tid = threadIdx.x;
  const int g = bid*256 + tid;         // 0..65535
  const int b = g >> 13, m = g & (NN - 1);

  float vc, vr;
  if (use_part) {
    vc = -3.0e38f;
#pragma unroll 8
    for (int nt = 0; nt < 64; ++nt)
      vc = fmaxf(vc, colpart[(size_t)((b << 6) | nt) * NN + m]);
    const int nt = m >> 7, r = m & 127;
    float r0 = rowpart[(size_t)((0 << 9) | (b << 6) | nt) * 128 + r];
    float r1 = rowpart[(size_t)((1 << 9) | (b << 6) | nt) * 128 + r];
    vr = fmaxf(r0, r1);
  } else {
    vc = dec_ord(colmax_u[g]);
    vr = dec_ord(rowmax_u[g]);
  }
  float s = sqrtf(fmaxf(-2.f * vc, 0.f))   // nearest-x for this y
          + sqrtf(fmaxf(-2.f * vr, 0.f));  // nearest-y for this x

#pragma unroll
  for (int d = 1; d < 64; d <<= 1) s += __shfl_xor(s, d);
  __shared__ float wsum[4];
  if ((tid & 63) == 0) wsum[tid >> 6] = s;
  __syncthreads();
  if (tid == 0)
    atomicAdd(out, (wsum[0] + wsum[1] + wsum[2] + wsum[3]) * (1.0f / 65536.0f));
}

// ---------------------------------------------------------------------------
extern "C" void kernel_launch(void* const* d_in, const int* in_sizes, int n_in,
                              void* d_out, int out_size, void* d_ws, size_t ws_size,
                              hipStream_t stream) {
  const float* x = (const float*)d_in[0];
  const float* y = (const float*)d_in[1];
  float* out = (float*)d_out;

  char* p = (char*)d_ws;
  u16* xs = (u16*)p;            p += (size_t)512 * 16384;   // 8 MiB
  u16* ys = (u16*)p;            p += (size_t)512 * 16384;   // 8 MiB
  float* x2h = (float*)p;       p += (size_t)65536 * 4;
  float* y2h = (float*)p;       p += (size_t)65536 * 4;
  char* tail = p;
  // partial path: colpart 16 MiB + rowpart 512 KiB
  float* colpart = (float*)tail;
  float* rowpart = (float*)(tail + (size_t)512 * 8192 * 4);
  // atomic fallback: two 256 KiB ordered-uint max buffers
  unsigned* colmax_u = (unsigned*)tail;
  unsigned* rowmax_u = (unsigned*)(tail + (size_t)65536 * 4);
  const size_t need_part = (size_t)(tail - (char*)d_ws) +
                           (size_t)512 * 8192 * 4 + (size_t)1024 * 128 * 4;
  const int use_part = (ws_size >= need_part) ? 1 : 0;

  pre_kernel<<<dim3(1024), dim3(256), 0, stream>>>(x, y, xs, ys, x2h, y2h,
                                                   rowmax_u, colmax_u, out,
                                                   use_part);
  main_kernel<<<dim3(1024), dim3(256), 0, stream>>>(xs, ys, x2h, y2h,
                                                    rowpart, colpart,
                                                    rowmax_u, colmax_u,
                                                    use_part);
  reduce_kernel<<<dim3(256), dim3(256), 0, stream>>>(rowpart, colpart,
                                                     rowmax_u, colmax_u,
                                                     out, use_part);
}

// Round 13
// 199.749 us; speedup vs baseline: 3.3209x; 1.2126x over previous
//
#include <hip/hip_runtime.h>
#include <cstdint>
#include <cstddef>

typedef unsigned short u16;
typedef __attribute__((ext_vector_type(8))) short short8;
typedef __attribute__((ext_vector_type(8))) u16 ushort8;
typedef __attribute__((ext_vector_type(4))) float float4_t;

#define BB 8
#define NN 8192
#define DD 64
#define NRT 128              // 64-row tiles per batch
#define TILE_SHORTS 8192     // 128 points * 64 k (bf16)
#define LDS_STRIDE 68        // pre_kernel stage stride
#define SLICE_U16 2176       // per-wave LDS slice: 2048 data + 64 y2 + pad

__device__ inline u16 f32_to_bf16(float f) {
  unsigned u = __float_as_uint(f);
  u += 0x7FFFu + ((u >> 16) & 1u);   // RNE
  return (u16)(u >> 16);
}

__device__ inline unsigned enc_ord(float f) {
  unsigned u = __float_as_uint(f);
  return (u & 0x80000000u) ? ~u : (u | 0x80000000u);
}
__device__ inline float dec_ord(unsigned u) {
  return __uint_as_float((u & 0x80000000u) ? (u & 0x7fffffffu) : ~u);
}

// ---------------------------------------------------------------------------
// K1: one block = one 128x64 tile. Coalesced read-once -> LDS -> swizzled
// bf16 tile (MFMA fragment chunk order) + 0.5*|row|^2. Zeroes out[] and, in
// the fallback path, the ordered-uint max buffers.  [verified R6-R12]
// Chunk layout per tile: [I(8)][s(2)] chunks of 1KB; within a chunk lane
// l (l=qq*16+rl) holds point I*16+rl, k = s*32+qq*8+j (j=0..7, 16B).
// ---------------------------------------------------------------------------
__global__ __launch_bounds__(256) void pre_kernel(
    const float* __restrict__ x, const float* __restrict__ y,
    u16* __restrict__ xs, u16* __restrict__ ys,
    float* __restrict__ x2h, float* __restrict__ y2h,
    unsigned* __restrict__ rowmax_u, unsigned* __restrict__ colmax_u,
    float* __restrict__ out, const int use_part)
{
  __shared__ float stage[128 * LDS_STRIDE];   // 34 KB

  const int bid = blockIdx.x;          // 1024: 0..511 -> x, 512..1023 -> y
  const int tid = threadIdx.x;

  if (!use_part) {
    if (bid < 256)      colmax_u[(bid << 8) | tid] = 0u;
    else if (bid < 512) rowmax_u[((bid - 256) << 8) | tid] = 0u;
  }
  if (bid == 0 && tid == 0) out[0] = 0.f;

  const bool isY = bid >= 512;
  const int t = bid & 511;             // tile id = b*64 + nt
  const float* src = (isY ? y : x) + (size_t)t * (128 * DD);
  u16* dst = (isY ? ys : xs) + (size_t)t * TILE_SHORTS;
  float* s2 = (isY ? y2h : x2h) + t * 128;

#pragma unroll
  for (int c = 0; c < 8; ++c) {
    const int idx = c * 256 + tid;     // float4 index within tile (0..2047)
    float4 f = ((const float4*)src)[idx];
    const int r = idx >> 4, kc = idx & 15;
    *(float4*)&stage[r * LDS_STRIDE + kc * 4] = f;
  }
  __syncthreads();

  {
    const int r = tid >> 1, half = tid & 1;
    const float* rp = &stage[r * LDS_STRIDE + half * 32];
    float ss = 0.f;
#pragma unroll
    for (int k = 0; k < 8; ++k) {
      float4 f = *(const float4*)&rp[k * 4];
      ss += f.x*f.x + f.y*f.y + f.z*f.z + f.w*f.w;
    }
    ss += __shfl_xor(ss, 1);
    if (half == 0) s2[r] = 0.5f * ss;
  }

  {
    const int w = tid >> 6, lane = tid & 63;
    const int qq = lane >> 4, rl = lane & 15;
#pragma unroll
    for (int u = 0; u < 4; ++u) {
      const int chunk = w * 4 + u;
      const int I = chunk >> 1, s = chunk & 1;
      const float* rp = &stage[(I*16 + rl) * LDS_STRIDE + s*32 + qq*8];
      ushort8 o;
#pragma unroll
      for (int j = 0; j < 8; ++j) o[j] = f32_to_bf16(rp[j]);
      *(ushort8*)(dst + chunk*512 + lane*8) = o;
    }
  }
}

// ---------------------------------------------------------------------------
// K2: main — NEW SHAPE to break the register wall (R4/R6/R8/R12: the 128x32
// wave tile's ~214 live regs admit only the R3 code at 2 waves/SIMD):
//   block = 4 waves; all waves share the SAME 64 rows, each owns a disjoint
//   32-col slice of a 128-col group (= one ys tile per iteration).
//   B is staged via global_load_lds into PER-WAVE-PRIVATE double-buffered
//   4.2 KB LDS slices -> no __syncthreads in the loop; the only sync is a
//   manual s_waitcnt vmcnt(0) at iter top (drains last iter's staging while
//   this iter's staging stays in flight).  Persistent regs ~115-125 << 170
//   cap of (256,3) -> 3 blocks/CU with NO spill (R11's spill was demand
//   ~200 > 170, not the cap mechanism).
// acc = xy - x2/2 - y2/2 = -d^2/2 via exact fp32 C-init; both epilogues are
// pure max. Col partials -> bf16 colpart[b][rt][m] (R8-verified, absmax 0).
// Grid 3072 = 8 b (XCD-affine) x 128 rt x 3 h = exactly 4 rounds of 768.
// ---------------------------------------------------------------------------
__global__ __launch_bounds__(256, 3) void main_kernel(
    const u16* __restrict__ xs, const u16* __restrict__ ys,
    const float* __restrict__ x2h, const float* __restrict__ y2h,
    float* __restrict__ rowpart, u16* __restrict__ colpart,
    unsigned* __restrict__ rowmax_u, unsigned* __restrict__ colmax_u,
    const int use_part)
{
  __shared__ __align__(16) u16 ytile[2][4][SLICE_U16];   // 34.8 KB
  __shared__ float rowbuf[4][64];

  const int bid = blockIdx.x;          // 3072
  const int b   = bid & 7;             // XCD-affine
  const int rt  = (bid >> 3) & 127;    // 64-row tile
  const int h   = bid >> 10;           // 0..2 column third
  const int mt_start = (h == 0) ? 0 : (h == 1 ? 22 : 43);
  const int mt_end   = (h == 0) ? 22 : (h == 1 ? 43 : 64);
  const int tid = threadIdx.x;
  const int w = tid >> 6, lane = tid & 63;   // w = 32-col slice owner
  const int l15 = lane & 15, q = lane >> 4;

  // ---- A fragments: 64 rows, both K-halves (32 VGPR) ----
  const u16* xs_tile = xs + (size_t)((b << 6) | (rt >> 1)) * TILE_SHORTS;
  short8 afr[4][2];
#pragma unroll
  for (int i = 0; i < 4; ++i)
#pragma unroll
    for (int s = 0; s < 2; ++s)
      afr[i][s] = *(const short8*)(xs_tile + ((((rt & 1)*4 + i)*2) + s)*512 + lane*8);

  // ---- -x2/2 per row (fp32 exact; combined with -y2/2 in C-init) ----
  float4_t negx2[4];
  const float* x2b = x2h + b*NN + rt*64;
#pragma unroll
  for (int i = 0; i < 4; ++i) {
    float4_t v = *(const float4_t*)(x2b + i*16 + q*4);
    negx2[i] = {-v[0], -v[1], -v[2], -v[3]};
  }

  float rowmax[4][4];
#pragma unroll
  for (int i = 0; i < 4; ++i)
#pragma unroll
    for (int r = 0; r < 4; ++r) rowmax[i][r] = -3.0e38f;

  const float* y2b = y2h + b*NN;
  const u16* ys_b  = ys + (size_t)(b << 6) * TILE_SHORTS;
  u16* colp        = colpart + (size_t)(b*NRT + rt) * NN;
  unsigned* colu   = colmax_u + b*NN;

  // Stage ys tile MT: wave w's 32 points = chunks 4w..4w+3 (4 KB contiguous),
  // plus its 128 B of y2 (fp32), into private slice ytile[BUF][w].
#define STAGE(MT, BUF)                                                         \
  do {                                                                         \
    const u16* g_ = ys_b + (size_t)(MT) * TILE_SHORTS + (w*4)*512;             \
    _Pragma("unroll") for (int c = 0; c < 4; ++c)                              \
      __builtin_amdgcn_global_load_lds(                                        \
          (const __attribute__((address_space(1))) void*)(g_ + c*512 + lane*8),\
          (__attribute__((address_space(3))) void*)(&ytile[BUF][w][c*512]),    \
          16, 0, 0);                                                           \
    if (lane < 8)                                                              \
      __builtin_amdgcn_global_load_lds(                                        \
          (const __attribute__((address_space(1))) void*)(y2b + (MT)*128 + w*32 + lane*4), \
          (__attribute__((address_space(3))) void*)(&ytile[BUF][w][2048]),     \
          16, 0, 0);                                                           \
  } while (0)

  STAGE(mt_start, 0);

  for (int mt = mt_start; mt < mt_end; ++mt) {
    const int buf = (mt - mt_start) & 1;
    __builtin_amdgcn_s_waitcnt(0x0f70);   // vmcnt(0): staging of `buf` landed
    if (mt + 1 < mt_end) STAGE(mt + 1, buf ^ 1);

    const float* y2s = (const float*)&ytile[buf][w][2048];
    float cmax[2];
#pragma unroll
    for (int j = 0; j < 2; ++j) {
      short8 bf0 = *(const short8*)(&ytile[buf][w][(j*2 + 0)*512 + lane*8]);
      short8 bf1 = *(const short8*)(&ytile[buf][w][(j*2 + 1)*512 + lane*8]);
      const float y2j = y2s[j*16 + l15];
      float4_t acc[4];
#pragma unroll
      for (int i = 0; i < 4; ++i) {
        float4_t ci = {negx2[i][0] - y2j, negx2[i][1] - y2j,
                       negx2[i][2] - y2j, negx2[i][3] - y2j};
        acc[i] = __builtin_amdgcn_mfma_f32_16x16x32_bf16(afr[i][0], bf0, ci, 0, 0, 0);
      }
#pragma unroll
      for (int i = 0; i < 4; ++i)
        acc[i] = __builtin_amdgcn_mfma_f32_16x16x32_bf16(afr[i][1], bf1, acc[i], 0, 0, 0);

      // col side: pure max over rows in-lane
      float m0 = fmaxf(fmaxf(acc[0][0], acc[0][1]), fmaxf(acc[0][2], acc[0][3]));
#pragma unroll
      for (int i = 1; i < 4; ++i)
        m0 = fmaxf(m0, fmaxf(fmaxf(acc[i][0], acc[i][1]),
                             fmaxf(acc[i][2], acc[i][3])));
      cmax[j] = m0;

      // row side: pure max (acc = -d^2/2)
#pragma unroll
      for (int i = 0; i < 4; ++i)
#pragma unroll
        for (int r = 0; r < 4; ++r)
          rowmax[i][r] = fmaxf(rowmax[i][r], acc[i][r]);
    }

    // col-max: combine q-groups via shuffles; wave-private, no barrier
#pragma unroll
    for (int j = 0; j < 2; ++j) {
      cmax[j] = fmaxf(cmax[j], __shfl_xor(cmax[j], 16));
      cmax[j] = fmaxf(cmax[j], __shfl_xor(cmax[j], 32));
    }
    float cv = (q & 1) ? cmax[1] : cmax[0];
    const int m = (mt << 7) + w*32 + q*16 + l15;   // valid for q<2
    if (q < 2) {
      if (use_part) colp[m] = f32_to_bf16(cv);
      else          atomicMax(&colu[m], enc_ord(cv));
    }
  }
#undef STAGE

  // ---- row side finalize: shfl over cols (l15), then 4-wave LDS combine ----
#pragma unroll
  for (int i = 0; i < 4; ++i)
#pragma unroll
    for (int r = 0; r < 4; ++r) {
      float v = rowmax[i][r];
      v = fmaxf(v, __shfl_xor(v, 1));
      v = fmaxf(v, __shfl_xor(v, 2));
      v = fmaxf(v, __shfl_xor(v, 4));
      v = fmaxf(v, __shfl_xor(v, 8));
      rowmax[i][r] = v;
    }
  if (l15 == 0) {
#pragma unroll
    for (int i = 0; i < 4; ++i)
#pragma unroll
      for (int r = 0; r < 4; ++r)
        rowbuf[w][i*16 + q*4 + r] = rowmax[i][r];
  }
  __syncthreads();
  if (tid < 64) {
    float v = fmaxf(fmaxf(rowbuf[0][tid], rowbuf[1][tid]),
                    fmaxf(rowbuf[2][tid], rowbuf[3][tid]));   // -min(d^2)/2
    if (use_part)
      rowpart[((size_t)(h*8 + b) * NRT + rt) * 64 + tid] = v;
    else
      atomicMax(&rowmax_u[b*NN + rt*64 + tid], enc_ord(v));
  }
}

// ---------------------------------------------------------------------------
// K3: col combine over 128 rt (bf16) + sqrt; row combine over 3 h + sqrt;
// block sum; atomicAdd scaled result into out.
// ---------------------------------------------------------------------------
__global__ __launch_bounds__(256) void reduce_kernel(
    const float* __restrict__ rowpart, const u16* __restrict__ colpart,
    const unsigned* __restrict__ rowmax_u, const unsigned* __restrict__ colmax_u,
    float* __restrict__ out, const int use_part)
{
  const int bid = blockIdx.x;          // 256
  const int tid = threadIdx.x;
  const int g = bid*256 + tid;         // 0..65535
  const int b = g >> 13, m = g & (NN - 1);

  float vc, vr;
  if (use_part) {
    const u16* cp = colpart + (size_t)b * NRT * NN + m;
    vc = -3.0e38f;
#pragma unroll 8
    for (int rt = 0; rt < NRT; ++rt) {
      unsigned u = cp[(size_t)rt * NN];
      vc = fmaxf(vc, __uint_as_float(u << 16));
    }
    const int rt2 = m >> 6, r = m & 63;
    float r0 = rowpart[((size_t)(0*8 + b) * NRT + rt2) * 64 + r];
    float r1 = rowpart[((size_t)(1*8 + b) * NRT + rt2) * 64 + r];
    float r2 = rowpart[((size_t)(2*8 + b) * NRT + rt2) * 64 + r];
    vr = fmaxf(fmaxf(r0, r1), r2);
  } else {
    vc = dec_ord(colmax_u[g]);
    vr = dec_ord(rowmax_u[g]);
  }
  float s = sqrtf(fmaxf(-2.f * vc, 0.f))   // nearest-x for this y
          + sqrtf(fmaxf(-2.f * vr, 0.f));  // nearest-y for this x

#pragma unroll
  for (int d = 1; d < 64; d <<= 1) s += __shfl_xor(s, d);
  __shared__ float wsum[4];
  if ((tid & 63) == 0) wsum[tid >> 6] = s;
  __syncthreads();
  if (tid == 0)
    atomicAdd(out, (wsum[0] + wsum[1] + wsum[2] + wsum[3]) * (1.0f / 65536.0f));
}

// ---------------------------------------------------------------------------
extern "C" void kernel_launch(void* const* d_in, const int* in_sizes, int n_in,
                              void* d_out, int out_size, void* d_ws, size_t ws_size,
                              hipStream_t stream) {
  const float* x = (const float*)d_in[0];
  const float* y = (const float*)d_in[1];
  float* out = (float*)d_out;

  char* p = (char*)d_ws;
  u16* xs = (u16*)p;            p += (size_t)512 * 16384;   // 8 MiB
  u16* ys = (u16*)p;            p += (size_t)512 * 16384;   // 8 MiB
  float* x2h = (float*)p;       p += (size_t)65536 * 4;
  float* y2h = (float*)p;       p += (size_t)65536 * 4;
  char* tail = p;
  // partial path: colpart bf16 16 MiB + rowpart 768 KiB
  u16* colpart = (u16*)tail;
  float* rowpart = (float*)(tail + (size_t)8 * NRT * NN * 2);
  // atomic fallback: two 256 KiB ordered-uint max buffers
  unsigned* colmax_u = (unsigned*)tail;
  unsigned* rowmax_u = (unsigned*)(tail + (size_t)65536 * 4);
  const size_t need_part = (size_t)(tail - (char*)d_ws) +
                           (size_t)8 * NRT * NN * 2 + (size_t)3 * 8 * NRT * 64 * 4;
  const int use_part = (ws_size >= need_part) ? 1 : 0;

  pre_kernel<<<dim3(1024), dim3(256), 0, stream>>>(x, y, xs, ys, x2h, y2h,
                                                   rowmax_u, colmax_u, out,
                                                   use_part);
  main_kernel<<<dim3(3072), dim3(256), 0, stream>>>(xs, ys, x2h, y2h,
                                                    rowpart, colpart,
                                                    rowmax_u, colmax_u,
                                                    use_part);
  reduce_kernel<<<dim3(256), dim3(256), 0, stream>>>(rowpart, colpart,
                                                     rowmax_u, colmax_u,
                                                     out, use_part);
}

// Round 14
// 196.593 us; speedup vs baseline: 3.3742x; 1.0161x over previous
//
#include <hip/hip_runtime.h>
#include <cstdint>
#include <cstddef>

typedef unsigned short u16;
typedef __attribute__((ext_vector_type(8))) short short8;
typedef __attribute__((ext_vector_type(8))) u16 ushort8;
typedef __attribute__((ext_vector_type(4))) float float4_t;

#define BB 8
#define NN 8192
#define DD 64
#define NRT 128              // 64-row tiles per batch
#define NIT 32               // col sweep: 32 iters x 256 cols
#define TILE_SHORTS 8192     // 128 points * 64 k (bf16)
#define LDS_STRIDE 68        // pre_kernel stage stride
#define SLICE_U16 4096       // per-wave LDS slice: 64 cols x 64 k bf16 = 8 KB

__device__ inline u16 f32_to_bf16(float f) {
  unsigned u = __float_as_uint(f);
  u += 0x7FFFu + ((u >> 16) & 1u);   // RNE
  return (u16)(u >> 16);
}

__device__ inline unsigned enc_ord(float f) {
  unsigned u = __float_as_uint(f);
  return (u & 0x80000000u) ? ~u : (u | 0x80000000u);
}
__device__ inline float dec_ord(unsigned u) {
  return __uint_as_float((u & 0x80000000u) ? (u & 0x7fffffffu) : ~u);
}

// ---------------------------------------------------------------------------
// K1: one block = one 128x64 tile. Coalesced read-once -> LDS -> swizzled
// bf16 tile (MFMA fragment chunk order) + 0.5*|row|^2. Zeroes out[] and, in
// the fallback path, the ordered-uint col-max buffer.  [verified R6-R13]
// ---------------------------------------------------------------------------
__global__ __launch_bounds__(256) void pre_kernel(
    const float* __restrict__ x, const float* __restrict__ y,
    u16* __restrict__ xs, u16* __restrict__ ys,
    float* __restrict__ x2h, float* __restrict__ y2h,
    unsigned* __restrict__ colmax_u, float* __restrict__ out,
    const int use_part)
{
  __shared__ float stage[128 * LDS_STRIDE];   // 34 KB

  const int bid = blockIdx.x;          // 1024: 0..511 -> x, 512..1023 -> y
  const int tid = threadIdx.x;

  if (!use_part && bid < 256) colmax_u[(bid << 8) | tid] = 0u;
  if (bid == 0 && tid == 0) out[0] = 0.f;

  const bool isY = bid >= 512;
  const int t = bid & 511;             // tile id = b*64 + nt
  const float* src = (isY ? y : x) + (size_t)t * (128 * DD);
  u16* dst = (isY ? ys : xs) + (size_t)t * TILE_SHORTS;
  float* s2 = (isY ? y2h : x2h) + t * 128;

#pragma unroll
  for (int c = 0; c < 8; ++c) {
    const int idx = c * 256 + tid;     // float4 index within tile (0..2047)
    float4 f = ((const float4*)src)[idx];
    const int r = idx >> 4, kc = idx & 15;
    *(float4*)&stage[r * LDS_STRIDE + kc * 4] = f;
  }
  __syncthreads();

  {
    const int r = tid >> 1, half = tid & 1;
    const float* rp = &stage[r * LDS_STRIDE + half * 32];
    float ss = 0.f;
#pragma unroll
    for (int k = 0; k < 8; ++k) {
      float4 f = *(const float4*)&rp[k * 4];
      ss += f.x*f.x + f.y*f.y + f.z*f.z + f.w*f.w;
    }
    ss += __shfl_xor(ss, 1);
    if (half == 0) s2[r] = 0.5f * ss;
  }

  {
    const int w = tid >> 6, lane = tid & 63;
    const int qq = lane >> 4, rl = lane & 15;
#pragma unroll
    for (int u = 0; u < 4; ++u) {
      const int chunk = w * 4 + u;
      const int I = chunk >> 1, s = chunk & 1;
      const float* rp = &stage[(I*16 + rl) * LDS_STRIDE + s*32 + qq*8];
      ushort8 o;
#pragma unroll
      for (int j = 0; j < 8; ++j) o[j] = f32_to_bf16(rp[j]);
      *(ushort8*)(dst + chunk*512 + lane*8) = o;
    }
  }
}

// ---------------------------------------------------------------------------
// K2: main — shape chosen to make in-wave pipelining FIT (R4/R6/R8/R12: the
// 128x32 tile has zero register slack; R8/R13: small tiles lose the
// MFMA:VALU ratio). Wave = 64 rows x 64 cols -> 32 MFMA/iter (R3 ratio),
// B via global_load_lds into per-wave-private double-buffered 8 KB LDS
// slices (frees R3's 64 regs of B prefetch). Persistent regs ~145 << 256 ->
// TWO acc banks + j-interleave fit with slack: MFMA(j+1) issues while
// EPI(j) (pure max; C-init = exact fp32 -(x^2+y^2)/2) drains on VALU.
// Barrier-free loop; iter-top s_waitcnt vmcnt(5) (store + y2 prefetch stay
// in flight — never drain to 0). LDS 64 KB -> 2 blocks/CU; the bet is ILP.
// Block owns its 64 rows completely -> a_min direct. Col partials bf16
// colpart[b][rt][m] (R8-verified, absmax 0). Grid 1024 = 8 b x 128 rt.
// ---------------------------------------------------------------------------
__global__ __launch_bounds__(256, 2) void main_kernel(
    const u16* __restrict__ xs, const u16* __restrict__ ys,
    const float* __restrict__ x2h, const float* __restrict__ y2h,
    float* __restrict__ a_min, u16* __restrict__ colpart,
    unsigned* __restrict__ colmax_u, const int use_part)
{
  __shared__ __align__(16) u16 ytile[2][4][SLICE_U16];   // exactly 64 KB

  const int bid = blockIdx.x;          // 1024
  const int b   = bid & 7;             // XCD-affine
  const int rt  = bid >> 3;            // 64-row tile, 0..127
  const int tid = threadIdx.x;
  const int w = tid >> 6, lane = tid & 63;   // w = 64-col slice owner
  const int l15 = lane & 15, q = lane >> 4;

  // ---- A fragments: 64 rows, both K-halves (32 VGPR) ----
  const u16* xs_tile = xs + (size_t)((b << 6) | (rt >> 1)) * TILE_SHORTS;
  short8 afr[4][2];
#pragma unroll
  for (int i = 0; i < 4; ++i)
#pragma unroll
    for (int s = 0; s < 2; ++s)
      afr[i][s] = *(const short8*)(xs_tile + ((((rt & 1)*4 + i)*2) + s)*512 + lane*8);

  // ---- -x2/2 per row (fp32 exact; combined with -y2/2 in C-init) ----
  float4_t negx2[4];
  const float* x2b = x2h + b*NN + rt*64;
#pragma unroll
  for (int i = 0; i < 4; ++i) {
    float4_t v = *(const float4_t*)(x2b + i*16 + q*4);
    negx2[i] = {-v[0], -v[1], -v[2], -v[3]};
  }

  float rowmax[4][4];
#pragma unroll
  for (int i = 0; i < 4; ++i)
#pragma unroll
    for (int r = 0; r < 4; ++r) rowmax[i][r] = -3.0e38f;

  const float* y2b = y2h + b*NN;
  const u16* ys_b  = ys + (size_t)(b << 6) * TILE_SHORTS;
  u16* colp        = colpart + (size_t)(b*NRT + rt) * NN;
  unsigned* colu   = colmax_u + b*NN;

  // Stage iter IT: wave w needs cols IT*256 + w*64 + [0,64) = contiguous
  // 8 KB of ys tile (2*IT + (w>>1)), point-half (w&1).
#define STAGE(IT, BUF)                                                         \
  do {                                                                         \
    const u16* g_ = ys_b + (size_t)(2*(IT) + (w >> 1))*TILE_SHORTS             \
                    + (w & 1)*4096;                                            \
    _Pragma("unroll") for (int c = 0; c < 8; ++c)                              \
      __builtin_amdgcn_global_load_lds(                                        \
          (const __attribute__((address_space(1))) void*)(g_ + c*512 + lane*8),\
          (__attribute__((address_space(3))) void*)(&ytile[BUF][w][c*512]),    \
          16, 0, 0);                                                           \
  } while (0)

  // MFMA stage j from slice; acc = xy - x2/2 - y2/2 = -d^2/2
#define MSTAGE(ACC, SL, J, Y2J)                                                \
  do {                                                                         \
    short8 bf0_ = *(const short8*)(&(SL)[((J)*2 + 0)*512 + lane*8]);           \
    short8 bf1_ = *(const short8*)(&(SL)[((J)*2 + 1)*512 + lane*8]);           \
    const float y2_ = (Y2J);                                                   \
    _Pragma("unroll") for (int i = 0; i < 4; ++i) {                            \
      float4_t ci = {negx2[i][0] - y2_, negx2[i][1] - y2_,                     \
                     negx2[i][2] - y2_, negx2[i][3] - y2_};                    \
      ACC[i] = __builtin_amdgcn_mfma_f32_16x16x32_bf16(afr[i][0], bf0_, ci, 0, 0, 0); \
    }                                                                          \
    _Pragma("unroll") for (int i = 0; i < 4; ++i)                              \
      ACC[i] = __builtin_amdgcn_mfma_f32_16x16x32_bf16(afr[i][1], bf1_, ACC[i], 0, 0, 0); \
  } while (0)

  // epilogue: pure max; leaves col-max of 16 cols in CM
#define EPI(ACC, CM)                                                           \
  do {                                                                         \
    float m_ = fmaxf(fmaxf(ACC[0][0], ACC[0][1]), fmaxf(ACC[0][2], ACC[0][3]));\
    _Pragma("unroll") for (int i = 1; i < 4; ++i)                              \
      m_ = fmaxf(m_, fmaxf(fmaxf(ACC[i][0], ACC[i][1]),                        \
                           fmaxf(ACC[i][2], ACC[i][3])));                      \
    m_ = fmaxf(m_, __shfl_xor(m_, 16));                                        \
    m_ = fmaxf(m_, __shfl_xor(m_, 32));                                        \
    CM = m_;                                                                   \
    _Pragma("unroll") for (int i = 0; i < 4; ++i)                              \
      _Pragma("unroll") for (int r = 0; r < 4; ++r)                            \
        rowmax[i][r] = fmaxf(rowmax[i][r], ACC[i][r]);                         \
  } while (0)

  float4_t accA[4], accB[4];
  float y2cur[4], y2next[4];

  STAGE(0, 0);
#pragma unroll
  for (int j = 0; j < 4; ++j) y2cur[j] = y2b[w*64 + j*16 + l15];

  for (int it = 0; it < NIT; ++it) {
    const int buf = it & 1;
    // wait for this iter's staging (8 oldest); store + y2next stay in flight
    __builtin_amdgcn_s_waitcnt(0x0f75);   // vmcnt(5)
    if (it + 1 < NIT) {
      STAGE(it + 1, buf ^ 1);
#pragma unroll
      for (int j = 0; j < 4; ++j)
        y2next[j] = y2b[(it + 1)*256 + w*64 + j*16 + l15];
    }

    const u16* sl = &ytile[buf][w][0];
    float cm0, cm1, cm2, cm3;
    // j-interleaved 2-bank pipeline: EPI(j) overlaps MFMA(j+1) drain
    MSTAGE(accA, sl, 0, y2cur[0]);
    MSTAGE(accB, sl, 1, y2cur[1]);
    EPI(accA, cm0);
    MSTAGE(accA, sl, 2, y2cur[2]);
    EPI(accB, cm1);
    MSTAGE(accB, sl, 3, y2cur[3]);
    EPI(accA, cm2);
    EPI(accB, cm3);

    // one contiguous 128B bf16 store of 64 col-maxes per wave
    float lo = (q & 1) ? cm1 : cm0;
    float hi = (q & 1) ? cm3 : cm2;
    float cv = (q & 2) ? hi : lo;
    if (use_part) colp[it*256 + w*64 + lane] = f32_to_bf16(cv);
    else          atomicMax(&colu[it*256 + w*64 + lane], enc_ord(cv));

#pragma unroll
    for (int j = 0; j < 4; ++j) y2cur[j] = y2next[j];
  }
#undef STAGE
#undef MSTAGE
#undef EPI

  // ---- row side: shfl over cols (l15), 4-wave combine via reused LDS ----
#pragma unroll
  for (int i = 0; i < 4; ++i)
#pragma unroll
    for (int r = 0; r < 4; ++r) {
      float v = rowmax[i][r];
      v = fmaxf(v, __shfl_xor(v, 1));
      v = fmaxf(v, __shfl_xor(v, 2));
      v = fmaxf(v, __shfl_xor(v, 4));
      v = fmaxf(v, __shfl_xor(v, 8));
      rowmax[i][r] = v;
    }
  __syncthreads();                       // all waves done with ytile
  float* rowbuf = (float*)&ytile[0][0][0];   // reuse LDS (4x64 floats)
  if (l15 == 0) {
#pragma unroll
    for (int i = 0; i < 4; ++i)
#pragma unroll
      for (int r = 0; r < 4; ++r)
        rowbuf[w*64 + i*16 + q*4 + r] = rowmax[i][r];
  }
  __syncthreads();
  if (tid < 64) {
    float v = fmaxf(fmaxf(rowbuf[0*64 + tid], rowbuf[1*64 + tid]),
                    fmaxf(rowbuf[2*64 + tid], rowbuf[3*64 + tid]));
    a_min[b*NN + rt*64 + tid] = sqrtf(fmaxf(-2.f * v, 0.f));   // min d
  }
}

// ---------------------------------------------------------------------------
// K3: col combine over 128 rt (bf16) + sqrt, add a_min; block sum;
// atomicAdd scaled result into out.  [R8-verified structure]
// ---------------------------------------------------------------------------
__global__ __launch_bounds__(256) void reduce_kernel(
    const u16* __restrict__ colpart, const unsigned* __restrict__ colmax_u,
    const float* __restrict__ a_min, float* __restrict__ out,
    const int use_part)
{
  const int bid = blockIdx.x;          // 256
  const int tid = threadIdx.x;
  const int g = bid*256 + tid;         // 0..65535 = b*NN + m
  const int b = g >> 13, m = g & (NN - 1);

  float vc;
  if (use_part) {
    const u16* cp = colpart + (size_t)b * NRT * NN + m;
    vc = -3.0e38f;
#pragma unroll 8
    for (int rt = 0; rt < NRT; ++rt) {
      unsigned u = cp[(size_t)rt * NN];
      vc = fmaxf(vc, __uint_as_float(u << 16));
    }
  } else {
    vc = dec_ord(colmax_u[g]);
  }
  float s = sqrtf(fmaxf(-2.f * vc, 0.f))   // nearest-x for this y
          + a_min[g];                      // nearest-y for this x

#pragma unroll
  for (int d = 1; d < 64; d <<= 1) s += __shfl_xor(s, d);
  __shared__ float wsum[4];
  if ((tid & 63) == 0) wsum[tid >> 6] = s;
  __syncthreads();
  if (tid == 0)
    atomicAdd(out, (wsum[0] + wsum[1] + wsum[2] + wsum[3]) * (1.0f / 65536.0f));
}

// ---------------------------------------------------------------------------
extern "C" void kernel_launch(void* const* d_in, const int* in_sizes, int n_in,
                              void* d_out, int out_size, void* d_ws, size_t ws_size,
                              hipStream_t stream) {
  const float* x = (const float*)d_in[0];
  const float* y = (const float*)d_in[1];
  float* out = (float*)d_out;

  char* p = (char*)d_ws;
  u16* xs = (u16*)p;            p += (size_t)512 * 16384;   // 8 MiB
  u16* ys = (u16*)p;            p += (size_t)512 * 16384;   // 8 MiB
  float* x2h = (float*)p;       p += (size_t)65536 * 4;
  float* y2h = (float*)p;       p += (size_t)65536 * 4;
  float* a_min = (float*)p;     p += (size_t)65536 * 4;
  char* tail = p;
  // partial path: colpart bf16 = 8 * 128 * 8192 * 2 B = 16 MiB
  u16* colpart = (u16*)tail;
  unsigned* colmax_u = (unsigned*)tail;   // fallback alias (256 KiB)
  const size_t need_part = (size_t)(tail - (char*)d_ws) +
                           (size_t)8 * NRT * NN * 2;
  const int use_part = (ws_size >= need_part) ? 1 : 0;

  pre_kernel<<<dim3(1024), dim3(256), 0, stream>>>(x, y, xs, ys, x2h, y2h,
                                                   colmax_u, out, use_part);
  main_kernel<<<dim3(1024), dim3(256), 0, stream>>>(xs, ys, x2h, y2h, a_min,
                                                    colpart, colmax_u,
                                                    use_part);
  reduce_kernel<<<dim3(256), dim3(256), 0, stream>>>(colpart, colmax_u,
                                                     a_min, out, use_part);
}